// Round 3
// baseline (105.422 us; speedup 1.0000x reference)
//
#include <hip/hip_runtime.h>

// Direct-Form-II biquad over [B=64][T=262144] as a SINGLE-PASS decoupled-
// lookback affine scan.
//   v[t+1] = A v[t] + c x[t],  A = [[-a1,1],[-a2,0]],  out[t] = b0 x[t] + v0[t]
// 2048 blocks; block g: batch b=g>>5, chain position k=g&31, tile = 8192
// contiguous samples. Each block publishes its zero-init tile aggregate
// BEFORE waiting (deadlock-free), then composes all <=31 predecessor
// aggregates lane-parallel in one wave. x read once, out written once.

constexpr int BATCH = 64;
constexpr int T_LEN = 262144;
constexpr int TPB   = 256;            // threads per block
constexpr int LPT   = 32;             // samples per thread
constexpr int TILE  = TPB * LPT;      // 8192 samples per block
constexpr int NBPB  = T_LEN / TILE;   // 32 blocks per batch chain
constexpr int NB    = BATCH * NBPB;   // 2048 blocks

#define MATSQ(m00, m01, m10, m11)                                  \
    {                                                              \
        float n00 = fmaf(m00, m00, m01 * m10);                     \
        float n01 = fmaf(m00, m01, m01 * m11);                     \
        float n10 = fmaf(m10, m00, m11 * m10);                     \
        float n11 = fmaf(m10, m01, m11 * m11);                     \
        m00 = n00; m01 = n01; m10 = n10; m11 = n11;                \
    }

__device__ __forceinline__ unsigned long long pack2(float a, float b) {
    return (unsigned long long)__float_as_uint(a) |
           ((unsigned long long)__float_as_uint(b) << 32);
}

__global__ __launch_bounds__(256) void init_flags(unsigned* __restrict__ flags) {
    flags[blockIdx.x * 256 + threadIdx.x] = 0u;
}

__global__ __launch_bounds__(TPB) void biquad_lookback(
    const float* __restrict__ x, float* __restrict__ out,
    unsigned* __restrict__ flags, unsigned long long* __restrict__ aggs,
    const float* __restrict__ pb0, const float* __restrict__ pb1,
    const float* __restrict__ pb2, const float* __restrict__ pa1,
    const float* __restrict__ pa2)
{
    __shared__ float lds[TPB][33];          // padded tile (33.8 KB)
    __shared__ float sp0[TPB], sp1[TPB];    // scan scratch / broadcast

    const int tid  = threadIdx.x;
    const int lane = tid & 63;
    const int g    = blockIdx.x;
    const int b    = g >> 5;                // batch
    const int k    = g & (NBPB - 1);        // chain position

    const float b0 = *pb0, b1 = *pb1, b2 = *pb2;
    const float a1 = *pa1, a2 = *pa2;
    const float na1 = -a1, na2 = -a2;

    // ---- stage tile: 8 coalesced float4 loads per thread ----
    const size_t base = (size_t)b * T_LEN + (size_t)k * TILE;
    const float4* src = reinterpret_cast<const float4*>(x + base);
#pragma unroll
    for (int it = 0; it < 8; ++it) {
        int idx = it * TPB + tid;
        float4 v = src[idx];
        int e = idx * 4, c = e >> 5, t = e & 31;
        lds[c][t] = v.x; lds[c][t + 1] = v.y;
        lds[c][t + 2] = v.z; lds[c][t + 3] = v.w;
    }
    __syncthreads();

    // ---- per-thread zero-init chunk scan (row tid) ----
    float p0 = 0.f, p1 = 0.f;
#pragma unroll
    for (int t = 0; t < LPT; ++t) {
        float xv = lds[tid][t];
        float o  = fmaf(xv, b0, p0);
        float n0 = fmaf(na1, o, fmaf(xv, b1, p1));
        p1 = fmaf(na2, o, xv * b2);
        p0 = n0;
    }

    // ---- block-internal affine scan over 256 thread-carries ----
    // M = A^LPT = A^32 (5 squarings from A)
    float m00 = -a1, m01 = 1.f, m10 = -a2, m11 = 0.f;
#pragma unroll
    for (int s = 0; s < 5; ++s) MATSQ(m00, m01, m10, m11);

    float w00 = m00, w01 = m01, w10 = m10, w11 = m11;
    // in-wave rounds d = 1..32
    for (int d = 1; d < 64; d <<= 1) {
        float o0 = __shfl_up(p0, d);
        float o1 = __shfl_up(p1, d);
        if (lane >= d) {
            p0 = fmaf(w00, o0, fmaf(w01, o1, p0));
            p1 = fmaf(w10, o0, fmaf(w11, o1, p1));
        }
        MATSQ(w00, w01, w10, w11);
    }
    // cross-wave rounds d = 64, 128
    for (int d = 64; d < 256; d <<= 1) {
        sp0[tid] = p0; sp1[tid] = p1;
        __syncthreads();
        float o0 = 0.f, o1 = 0.f;
        const bool has = (tid >= d);
        if (has) { o0 = sp0[tid - d]; o1 = sp1[tid - d]; }
        __syncthreads();
        if (has) {
            p0 = fmaf(w00, o0, fmaf(w01, o1, p0));
            p1 = fmaf(w10, o0, fmaf(w11, o1, p1));
        }
        MATSQ(w00, w01, w10, w11);
    }

    sp0[tid] = p0; sp1[tid] = p1;
    __syncthreads();
    const float agg0 = sp0[TPB - 1], agg1 = sp1[TPB - 1];  // block aggregate
    float q0 = 0.f, q1 = 0.f;                               // excl. prefix
    if (tid > 0) { q0 = sp0[tid - 1]; q1 = sp1[tid - 1]; }

    // ---- publish aggregate BEFORE waiting (deadlock-free) ----
    if (tid == 0) {
        __hip_atomic_store(&aggs[g], pack2(agg0, agg1),
                           __ATOMIC_RELAXED, __HIP_MEMORY_SCOPE_AGENT);
        __hip_atomic_store(&flags[g], 1u,
                           __ATOMIC_RELEASE, __HIP_MEMORY_SCOPE_AGENT);
    }
    __syncthreads();   // everyone has read q/agg from sp before reuse

    // ---- lookback: wave 0 composes all k predecessor aggregates ----
    float s0 = 0.f, s1 = 0.f;
    if (k > 0) {
        if (tid < 64) {
            const int j = k - 1 - lane;          // pred chain position
            float e0 = 0.f, e1 = 0.f;
            if (j >= 0) {
                const int pg = (b << 5) + j;
                while (__hip_atomic_load(&flags[pg], __ATOMIC_ACQUIRE,
                                         __HIP_MEMORY_SCOPE_AGENT) == 0u)
                    __builtin_amdgcn_s_sleep(2);
                unsigned long long d = __hip_atomic_load(
                    &aggs[pg], __ATOMIC_RELAXED, __HIP_MEMORY_SCOPE_AGENT);
                e0 = __uint_as_float((unsigned)d);
                e1 = __uint_as_float((unsigned)(d >> 32));
            }
            // Wb = A^TILE = A^8192 (8 more squarings from M = A^32)
            float t00 = m00, t01 = m01, t10 = m10, t11 = m11;
#pragma unroll
            for (int s = 0; s < 8; ++s) MATSQ(t00, t01, t10, t11);
            // term = Wb^lane * e   (lane = k-1-j distance; 5 bits suffice)
            float v0 = e0, v1 = e1;
#pragma unroll
            for (int bit = 0; bit < 5; ++bit) {
                if ((lane >> bit) & 1) {
                    float n0 = fmaf(t00, v0, t01 * v1);
                    float n1 = fmaf(t10, v0, t11 * v1);
                    v0 = n0; v1 = n1;
                }
                MATSQ(t00, t01, t10, t11);
            }
            // sum terms across the wave
            for (int m = 32; m; m >>= 1) {
                v0 += __shfl_xor(v0, m);
                v1 += __shfl_xor(v1, m);
            }
            if (lane == 0) { sp0[0] = v0; sp1[0] = v1; }
        }
        __syncthreads();
        s0 = sp0[0]; s1 = sp1[0];
    }

    // ---- per-thread true start state: v = A^(32*tid) * s + q ----
    float v0 = s0, v1 = s1;
    {
        float t00 = m00, t01 = m01, t10 = m10, t11 = m11;  // A^32
#pragma unroll
        for (int bit = 0; bit < 8; ++bit) {
            if ((tid >> bit) & 1) {
                float n0 = fmaf(t00, v0, t01 * v1);
                float n1 = fmaf(t10, v0, t11 * v1);
                v0 = n0; v1 = n1;
            }
            MATSQ(t00, t01, t10, t11);
        }
    }
    v0 += q0; v1 += q1;

    // ---- final recurrence, outputs in-place into the LDS tile ----
#pragma unroll
    for (int t = 0; t < LPT; ++t) {
        float xv = lds[tid][t];
        float o  = fmaf(xv, b0, v0);
        float n0 = fmaf(na1, o, fmaf(xv, b1, v1));
        v1 = fmaf(na2, o, xv * b2);
        v0 = n0;
        lds[tid][t] = o;
    }
    __syncthreads();

    // ---- coalesced store ----
    float4* dst = reinterpret_cast<float4*>(out + base);
#pragma unroll
    for (int it = 0; it < 8; ++it) {
        int idx = it * TPB + tid;
        int e = idx * 4, c = e >> 5, t = e & 31;
        float4 v;
        v.x = lds[c][t];     v.y = lds[c][t + 1];
        v.z = lds[c][t + 2]; v.w = lds[c][t + 3];
        dst[idx] = v;
    }
}

extern "C" void kernel_launch(void* const* d_in, const int* in_sizes, int n_in,
                              void* d_out, int out_size, void* d_ws, size_t ws_size,
                              hipStream_t stream) {
    const float* x   = (const float*)d_in[0];
    const float* pb0 = (const float*)d_in[1];
    const float* pb1 = (const float*)d_in[2];
    const float* pb2 = (const float*)d_in[3];
    const float* pa1 = (const float*)d_in[4];
    const float* pa2 = (const float*)d_in[5];
    float* out = (float*)d_out;

    // ws: flags (2048 u32 = 8 KB), then aggregates (2048 u64 = 16 KB)
    unsigned* flags = (unsigned*)d_ws;
    unsigned long long* aggs =
        (unsigned long long*)((char*)d_ws + NB * sizeof(unsigned));

    init_flags<<<NB / 256, 256, 0, stream>>>(flags);
    biquad_lookback<<<NB, TPB, 0, stream>>>(x, out, flags, aggs,
                                            pb0, pb1, pb2, pa1, pa2);
}

// Round 4
// 35.602 us; speedup vs baseline: 2.9611x; 2.9611x over previous
//
#include <hip/hip_runtime.h>

// Direct-Form-II biquad over [B=64][T=262144] as a SINGLE-PASS decoupled-
// lookback affine scan.
//   v[t+1] = A v[t] + c x[t],  A = [[-a1,1],[-a2,0]],  out[t] = b0 x[t] + v0[t]
// 2048 blocks; block g: batch b=g>>5, chain pos k=g&31, tile = 8192 samples.
// Sync is FENCE-FREE: each block's aggregate (v0,v1) is packed into one
// 64-bit word published with a RELAXED agent atomic store; readers spin on
// a RELAXED atomic load until the word != SENTINEL. Same-address atomicity
// makes this correct with no acquire/release (no buffer_inv / wbl2 storms).
// Sentinel = negative signaling-NaN pattern: finite biquad arithmetic on a
// stable filter (|poles| < 0.87 for |a1|,|a2| < 0.5) cannot produce it.

constexpr int BATCH = 64;
constexpr int T_LEN = 262144;
constexpr int TPB   = 256;            // threads per block
constexpr int LPT   = 32;             // samples per thread
constexpr int TILE  = TPB * LPT;      // 8192 samples per block
constexpr int NBPB  = T_LEN / TILE;   // 32 blocks per batch chain
constexpr int NB    = BATCH * NBPB;   // 2048 blocks

#define SENTINEL 0xFFF00001FFF00001ULL

#define MATSQ(m00, m01, m10, m11)                                  \
    {                                                              \
        float n00 = fmaf(m00, m00, m01 * m10);                     \
        float n01 = fmaf(m00, m01, m01 * m11);                     \
        float n10 = fmaf(m10, m00, m11 * m10);                     \
        float n11 = fmaf(m10, m01, m11 * m11);                     \
        m00 = n00; m01 = n01; m10 = n10; m11 = n11;                \
    }

__device__ __forceinline__ unsigned long long pack2(float a, float b) {
    return (unsigned long long)__float_as_uint(a) |
           ((unsigned long long)__float_as_uint(b) << 32);
}

__global__ __launch_bounds__(256) void init_aggs(unsigned long long* __restrict__ aggs) {
    int i = blockIdx.x * 256 + threadIdx.x;
    if (i < NB) aggs[i] = SENTINEL;
}

__global__ __launch_bounds__(TPB) void biquad_lookback(
    const float* __restrict__ x, float* __restrict__ out,
    unsigned long long* __restrict__ aggs,
    const float* __restrict__ pb0, const float* __restrict__ pb1,
    const float* __restrict__ pb2, const float* __restrict__ pa1,
    const float* __restrict__ pa2)
{
    __shared__ float lds[TPB][33];          // padded tile
    __shared__ float sp0[TPB], sp1[TPB];    // scan scratch / broadcast

    const int tid  = threadIdx.x;
    const int lane = tid & 63;
    const int g    = blockIdx.x;
    const int b    = g >> 5;                // batch
    const int k    = g & (NBPB - 1);        // chain position

    const float b0 = *pb0, b1 = *pb1, b2 = *pb2;
    const float a1 = *pa1, a2 = *pa2;
    const float na1 = -a1, na2 = -a2;

    // ---- stage tile: 8 coalesced float4 loads per thread ----
    const size_t base = (size_t)b * T_LEN + (size_t)k * TILE;
    const float4* src = reinterpret_cast<const float4*>(x + base);
#pragma unroll
    for (int it = 0; it < 8; ++it) {
        int idx = it * TPB + tid;
        float4 v = src[idx];
        int e = idx * 4, c = e >> 5, t = e & 31;
        lds[c][t] = v.x; lds[c][t + 1] = v.y;
        lds[c][t + 2] = v.z; lds[c][t + 3] = v.w;
    }
    __syncthreads();

    // ---- per-thread zero-init chunk scan (row tid) ----
    float p0 = 0.f, p1 = 0.f;
#pragma unroll
    for (int t = 0; t < LPT; ++t) {
        float xv = lds[tid][t];
        float o  = fmaf(xv, b0, p0);
        float n0 = fmaf(na1, o, fmaf(xv, b1, p1));
        p1 = fmaf(na2, o, xv * b2);
        p0 = n0;
    }

    // ---- block-internal affine scan over 256 thread-carries ----
    // M = A^LPT = A^32 (5 squarings from A)
    float m00 = -a1, m01 = 1.f, m10 = -a2, m11 = 0.f;
#pragma unroll
    for (int s = 0; s < 5; ++s) MATSQ(m00, m01, m10, m11);

    float w00 = m00, w01 = m01, w10 = m10, w11 = m11;
    for (int d = 1; d < 64; d <<= 1) {          // in-wave rounds
        float o0 = __shfl_up(p0, d);
        float o1 = __shfl_up(p1, d);
        if (lane >= d) {
            p0 = fmaf(w00, o0, fmaf(w01, o1, p0));
            p1 = fmaf(w10, o0, fmaf(w11, o1, p1));
        }
        MATSQ(w00, w01, w10, w11);
    }
    for (int d = 64; d < 256; d <<= 1) {        // cross-wave rounds
        sp0[tid] = p0; sp1[tid] = p1;
        __syncthreads();
        float o0 = 0.f, o1 = 0.f;
        const bool has = (tid >= d);
        if (has) { o0 = sp0[tid - d]; o1 = sp1[tid - d]; }
        __syncthreads();
        if (has) {
            p0 = fmaf(w00, o0, fmaf(w01, o1, p0));
            p1 = fmaf(w10, o0, fmaf(w11, o1, p1));
        }
        MATSQ(w00, w01, w10, w11);
    }

    sp0[tid] = p0; sp1[tid] = p1;
    __syncthreads();
    const float agg0 = sp0[TPB - 1], agg1 = sp1[TPB - 1];  // block aggregate
    float q0 = 0.f, q1 = 0.f;                               // excl. prefix
    if (tid > 0) { q0 = sp0[tid - 1]; q1 = sp1[tid - 1]; }

    // ---- publish aggregate: ONE relaxed 64-bit atomic (no fences) ----
    if (tid == 0) {
        __hip_atomic_store(&aggs[g], pack2(agg0, agg1),
                           __ATOMIC_RELAXED, __HIP_MEMORY_SCOPE_AGENT);
    }
    __syncthreads();   // sp reads done before sp0[0] reuse below

    // ---- lookback: wave 0 composes all k predecessor aggregates ----
    float s0 = 0.f, s1 = 0.f;
    if (k > 0) {
        if (tid < 64) {
            const int j = k - 1 - lane;          // pred chain position
            float e0 = 0.f, e1 = 0.f;
            if (j >= 0) {
                const unsigned long long* slot = &aggs[(b << 5) + j];
                unsigned long long d;
                while ((d = __hip_atomic_load(slot, __ATOMIC_RELAXED,
                                              __HIP_MEMORY_SCOPE_AGENT))
                       == SENTINEL)
                    __builtin_amdgcn_s_sleep(2);
                e0 = __uint_as_float((unsigned)d);
                e1 = __uint_as_float((unsigned)(d >> 32));
            }
            // Wb = A^TILE = A^8192 (8 more squarings from M = A^32)
            float t00 = m00, t01 = m01, t10 = m10, t11 = m11;
#pragma unroll
            for (int s = 0; s < 8; ++s) MATSQ(t00, t01, t10, t11);
            // term = Wb^lane * e   (distance = lane; 5 bits suffice)
            float v0 = e0, v1 = e1;
#pragma unroll
            for (int bit = 0; bit < 5; ++bit) {
                if ((lane >> bit) & 1) {
                    float n0 = fmaf(t00, v0, t01 * v1);
                    float n1 = fmaf(t10, v0, t11 * v1);
                    v0 = n0; v1 = n1;
                }
                MATSQ(t00, t01, t10, t11);
            }
            for (int m = 32; m; m >>= 1) {       // wave sum of terms
                v0 += __shfl_xor(v0, m);
                v1 += __shfl_xor(v1, m);
            }
            if (lane == 0) { sp0[0] = v0; sp1[0] = v1; }
        }
        __syncthreads();
        s0 = sp0[0]; s1 = sp1[0];
    }

    // ---- per-thread true start state: v = A^(32*tid) * s + q ----
    float v0 = s0, v1 = s1;
    {
        float t00 = m00, t01 = m01, t10 = m10, t11 = m11;  // A^32
#pragma unroll
        for (int bit = 0; bit < 8; ++bit) {
            if ((tid >> bit) & 1) {
                float n0 = fmaf(t00, v0, t01 * v1);
                float n1 = fmaf(t10, v0, t11 * v1);
                v0 = n0; v1 = n1;
            }
            MATSQ(t00, t01, t10, t11);
        }
    }
    v0 += q0; v1 += q1;

    // ---- final recurrence, outputs in-place into the LDS tile ----
#pragma unroll
    for (int t = 0; t < LPT; ++t) {
        float xv = lds[tid][t];
        float o  = fmaf(xv, b0, v0);
        float n0 = fmaf(na1, o, fmaf(xv, b1, v1));
        v1 = fmaf(na2, o, xv * b2);
        v0 = n0;
        lds[tid][t] = o;
    }
    __syncthreads();

    // ---- coalesced store ----
    float4* dst = reinterpret_cast<float4*>(out + base);
#pragma unroll
    for (int it = 0; it < 8; ++it) {
        int idx = it * TPB + tid;
        int e = idx * 4, c = e >> 5, t = e & 31;
        float4 v;
        v.x = lds[c][t];     v.y = lds[c][t + 1];
        v.z = lds[c][t + 2]; v.w = lds[c][t + 3];
        dst[idx] = v;
    }
}

extern "C" void kernel_launch(void* const* d_in, const int* in_sizes, int n_in,
                              void* d_out, int out_size, void* d_ws, size_t ws_size,
                              hipStream_t stream) {
    const float* x   = (const float*)d_in[0];
    const float* pb0 = (const float*)d_in[1];
    const float* pb1 = (const float*)d_in[2];
    const float* pb2 = (const float*)d_in[3];
    const float* pa1 = (const float*)d_in[4];
    const float* pa2 = (const float*)d_in[5];
    float* out = (float*)d_out;

    unsigned long long* aggs = (unsigned long long*)d_ws;  // 2048 x u64

    init_aggs<<<(NB + 255) / 256, 256, 0, stream>>>(aggs);
    biquad_lookback<<<NB, TPB, 0, stream>>>(x, out, aggs,
                                            pb0, pb1, pb2, pa1, pa2);
}